// Round 4
// baseline (274.077 us; speedup 1.0000x reference)
//
#include <hip/hip_runtime.h>
#include <math.h>

#define BB 8
#define SS 2048
#define HH 1024
#define DD 64
#define NCV 65

typedef __attribute__((ext_vector_type(8))) short bf16x8;
typedef __attribute__((ext_vector_type(4))) float f32x4;

#define MFMA16(a, b, c) __builtin_amdgcn_mfma_f32_16x16x32_bf16(a, b, c, 0, 0, 0)

__device__ __forceinline__ ushort bf16rne(float f) {
    uint u = __float_as_uint(f);
    uint r = (u + 0x7FFFu + ((u >> 16) & 1u)) >> 16;
    return (ushort)r;
}
__device__ __forceinline__ float bf2f(ushort h) {
    return __uint_as_float(((uint)h) << 16);
}

// score = (1 + acos(clip(cos)))^-65.5
// acos via A&S 4.4.46: acos(x) = sqrt(1-x)*P(x), |err| <= ~3e-8 abs on [0,1].
__device__ __forceinline__ float score_fn(float cosv) {
    float ax = fminf(fabsf(cosv), 1.0f - 1e-7f);
    float p = fmaf(ax, -0.0012624911f, 0.0066700901f);
    p = fmaf(ax, p, -0.0170881256f);
    p = fmaf(ax, p, 0.0308918810f);
    p = fmaf(ax, p, -0.0501743046f);
    p = fmaf(ax, p, 0.0889789874f);
    p = fmaf(ax, p, -0.2145988016f);
    p = fmaf(ax, p, 1.5707963050f);
    float r = sqrtf(1.0f - ax) * p;                       // acos(|x|)
    float g = (cosv >= 0.0f) ? r : (3.14159265358979f - r);
    return exp2f(-65.5f * log2f(1.0f + g));
}

// K0: split W into bf16 hi/lo, layout Wcat[n][j], n = mat*64+d. Also bcat.
__global__ __launch_bounds__(256) void k_prep(
    const float* __restrict__ Wq, const float* __restrict__ Wk, const float* __restrict__ Wv,
    const float* __restrict__ bq, const float* __restrict__ bk, const float* __restrict__ bv,
    ushort* __restrict__ Whi, ushort* __restrict__ Wlo, float* __restrict__ bcat)
{
    const int n = blockIdx.x;          // 0..191
    const int m = n >> 6, d = n & 63;
    const float* W = (m == 0) ? Wq : (m == 1 ? Wk : Wv);
    #pragma unroll
    for (int i = 0; i < 4; ++i) {
        int j = i * 256 + threadIdx.x;
        float f = W[(size_t)j * DD + d];
        ushort h = bf16rne(f);
        Whi[(size_t)n * HH + j] = h;
        Wlo[(size_t)n * HH + j] = bf16rne(f - bf2f(h));
    }
    if (n == 0 && threadIdx.x < 192) {
        int t = threadIdx.x, mm = t >> 6, dd = t & 63;
        const float* b = (mm == 0) ? bq : (mm == 1 ? bk : bv);
        bcat[t] = b[dd];
    }
}

// K1: q,k,v = l2norm(x @ W + b) via split-bf16 MFMA.
__global__ __launch_bounds__(256) void k_projmm(
    const float* __restrict__ x, const ushort* __restrict__ Whi,
    const ushort* __restrict__ Wlo, const float* __restrict__ bcat,
    ushort* __restrict__ qh, ushort* __restrict__ ql,
    ushort* __restrict__ kh, ushort* __restrict__ kl,
    float* __restrict__ vw)
{
    __shared__ __align__(16) char smem[32 * 193 * 4];
    __shared__ float rns[96];
    __shared__ float bsh[192];
    ushort* xhi = (ushort*)smem;                 // [32][128] bf16, XOR-swizzled 16B units
    ushort* xlo = xhi + 32 * 128;
    float* ctile = (float*)smem;                 // [32][193] epilogue (aliases xhi/xlo)

    const int t = threadIdx.x;
    const int lane = t & 63;
    const int wid = t >> 6;
    const int row0 = blockIdx.x * 32;
    if (t < 192) bsh[t] = bcat[t];

    f32x4 acc[2][3];
    #pragma unroll
    for (int ar = 0; ar < 2; ++ar)
        #pragma unroll
        for (int bc = 0; bc < 3; ++bc)
            acc[ar][bc] = (f32x4){0.f, 0.f, 0.f, 0.f};

    for (int ch = 0; ch < 8; ++ch) {
        const int j0 = ch * 128;
        __syncthreads();
        #pragma unroll
        for (int i = 0; i < 2; ++i) {
            int u = i * 256 + t;
            int row = u >> 4, uc = u & 15;
            const float* xp = &x[(size_t)(row0 + row) * HH + j0 + uc * 8];
            float4 a = *(const float4*)xp;
            float4 b = *(const float4*)(xp + 4);
            float fs[8] = {a.x, a.y, a.z, a.w, b.x, b.y, b.z, b.w};
            bf16x8 hv, lv;
            #pragma unroll
            for (int e = 0; e < 8; ++e) {
                ushort h = bf16rne(fs[e]);
                hv[e] = (short)h;
                lv[e] = (short)bf16rne(fs[e] - bf2f(h));
            }
            int su = uc ^ (row & 7);
            *(bf16x8*)(xhi + row * 128 + su * 8) = hv;
            *(bf16x8*)(xlo + row * 128 + su * 8) = lv;
        }
        __syncthreads();
        #pragma unroll
        for (int ks = 0; ks < 4; ++ks) {
            bf16x8 ah[2], al[2], bh[3], bl[3];
            #pragma unroll
            for (int ar = 0; ar < 2; ++ar) {
                int row = ar * 16 + (lane & 15);
                int su = (ks * 4 + (lane >> 4)) ^ (row & 7);
                ah[ar] = *(const bf16x8*)(xhi + row * 128 + su * 8);
                al[ar] = *(const bf16x8*)(xlo + row * 128 + su * 8);
            }
            const int koff = j0 + ks * 32 + (lane >> 4) * 8;
            #pragma unroll
            for (int bc = 0; bc < 3; ++bc) {
                int n = wid * 48 + bc * 16 + (lane & 15);
                bh[bc] = *(const bf16x8*)(Whi + (size_t)n * HH + koff);
                bl[bc] = *(const bf16x8*)(Wlo + (size_t)n * HH + koff);
            }
            #pragma unroll
            for (int ar = 0; ar < 2; ++ar)
                #pragma unroll
                for (int bc = 0; bc < 3; ++bc) {
                    acc[ar][bc] = MFMA16(ah[ar], bh[bc], acc[ar][bc]);
                    acc[ar][bc] = MFMA16(ah[ar], bl[bc], acc[ar][bc]);
                    acc[ar][bc] = MFMA16(al[ar], bh[bc], acc[ar][bc]);
                }
        }
    }
    __syncthreads();
    #pragma unroll
    for (int ar = 0; ar < 2; ++ar)
        #pragma unroll
        for (int bc = 0; bc < 3; ++bc) {
            int n = wid * 48 + bc * 16 + (lane & 15);
            #pragma unroll
            for (int r = 0; r < 4; ++r) {
                int row = ar * 16 + (lane >> 4) * 4 + r;
                ctile[row * 193 + n] = acc[ar][bc][r];
            }
        }
    __syncthreads();
    if (t < 96) {
        int mat = t >> 5, row = t & 31;
        float ss = 0.f;
        #pragma unroll 8
        for (int d = 0; d < 64; ++d) {
            float v = ctile[row * 193 + mat * 64 + d] + bsh[mat * 64 + d];
            ss = fmaf(v, v, ss);
        }
        rns[t] = 1.0f / fmaxf(sqrtf(ss), 1e-12f);
    }
    __syncthreads();
    #pragma unroll
    for (int i = 0; i < 24; ++i) {
        int idx = i * 256 + t;
        int row = idx / 192;
        int n = idx - row * 192;
        float v = (ctile[row * 193 + n] + bsh[n]) * rns[(n >> 6) * 32 + row];
        size_t off = (size_t)(row0 + row) * DD + (n & 63);
        if (n < 64) {
            ushort h = bf16rne(v);
            qh[off] = h; ql[off] = bf16rne(v - bf2f(h));
        } else if (n < 128) {
            ushort h = bf16rne(v);
            kh[off] = h; kl[off] = bf16rne(v - bf2f(h));
        } else {
            vw[off] = v;
        }
    }
}

// K2: colsum[b][k] = sum_q score(q,k).
// Grid = 8b * 64qt(32 rows) * 4ks = 2048 blocks, 256 threads.
// Wave w covers k in [ks*512 + w*128, +128).
__global__ __launch_bounds__(256) void k_colsum(
    const ushort* __restrict__ qh, const ushort* __restrict__ ql,
    const ushort* __restrict__ kh, const ushort* __restrict__ kl,
    float* __restrict__ colsum)
{
    const int t = threadIdx.x;
    const int lane = t & 63;
    const int w = t >> 6;
    const int bid = blockIdx.x;
    const int b  = bid >> 8;
    const int q0 = ((bid >> 2) & 63) * 32;
    const int kbase = (bid & 3) * 512 + w * 128;

    bf16x8 ah[2][2], al[2][2];
    #pragma unroll
    for (int rt = 0; rt < 2; ++rt)
        #pragma unroll
        for (int ks = 0; ks < 2; ++ks) {
            size_t off = (size_t)(b * SS + q0 + rt * 16 + (lane & 15)) * DD + ks * 32 + (lane >> 4) * 8;
            ah[rt][ks] = *(const bf16x8*)(qh + off);
            al[rt][ks] = *(const bf16x8*)(ql + off);
        }

    #pragma unroll
    for (int kt2 = 0; kt2 < 4; ++kt2) {
        const int kkA = kbase + kt2 * 32 + (lane & 15);
        const int kkB = kkA + 16;
        size_t roffA = (size_t)(b * SS + kkA) * DD + (lane >> 4) * 8;
        size_t roffB = (size_t)(b * SS + kkB) * DD + (lane >> 4) * 8;
        bf16x8 bhA0 = *(const bf16x8*)(kh + roffA);
        bf16x8 blA0 = *(const bf16x8*)(kl + roffA);
        bf16x8 bhA1 = *(const bf16x8*)(kh + roffA + 32);
        bf16x8 blA1 = *(const bf16x8*)(kl + roffA + 32);
        bf16x8 bhB0 = *(const bf16x8*)(kh + roffB);
        bf16x8 blB0 = *(const bf16x8*)(kl + roffB);
        bf16x8 bhB1 = *(const bf16x8*)(kh + roffB + 32);
        bf16x8 blB1 = *(const bf16x8*)(kl + roffB + 32);
        f32x4 a0A = (f32x4){0.f,0.f,0.f,0.f}, a1A = a0A, a0B = a0A, a1B = a0A;
        a0A = MFMA16(ah[0][0], bhA0, a0A); a1A = MFMA16(ah[1][0], bhA0, a1A);
        a0B = MFMA16(ah[0][0], bhB0, a0B); a1B = MFMA16(ah[1][0], bhB0, a1B);
        a0A = MFMA16(ah[0][1], bhA1, a0A); a1A = MFMA16(ah[1][1], bhA1, a1A);
        a0B = MFMA16(ah[0][1], bhB1, a0B); a1B = MFMA16(ah[1][1], bhB1, a1B);
        a0A = MFMA16(ah[0][0], blA0, a0A); a1A = MFMA16(ah[1][0], blA0, a1A);
        a0B = MFMA16(ah[0][0], blB0, a0B); a1B = MFMA16(ah[1][0], blB0, a1B);
        a0A = MFMA16(ah[0][1], blA1, a0A); a1A = MFMA16(ah[1][1], blA1, a1A);
        a0B = MFMA16(ah[0][1], blB1, a0B); a1B = MFMA16(ah[1][1], blB1, a1B);
        a0A = MFMA16(al[0][0], bhA0, a0A); a1A = MFMA16(al[1][0], bhA0, a1A);
        a0B = MFMA16(al[0][0], bhB0, a0B); a1B = MFMA16(al[1][0], bhB0, a1B);
        a0A = MFMA16(al[0][1], bhA1, a0A); a1A = MFMA16(al[1][1], bhA1, a1A);
        a0B = MFMA16(al[0][1], bhB1, a0B); a1B = MFMA16(al[1][1], bhB1, a1B);
        float sA = 0.f, sB = 0.f;
        #pragma unroll
        for (int r = 0; r < 4; ++r) {
            sA += score_fn(a0A[r]); sA += score_fn(a1A[r]);
            sB += score_fn(a0B[r]); sB += score_fn(a1B[r]);
        }
        sA += __shfl_xor(sA, 16, 64); sA += __shfl_xor(sA, 32, 64);
        sB += __shfl_xor(sB, 16, 64); sB += __shfl_xor(sB, 32, 64);
        if (lane < 16) {
            atomicAdd(&colsum[b * SS + kkA], sA);
            atomicAdd(&colsum[b * SS + kkB], sB);
        }
    }
}

// K3: c = colsum^-0.5; cvT[b][j][k] = bf16(c*v[k][j]) for j<64, row 64 = bf16(c).
__global__ __launch_bounds__(256) void k_cvc(
    const float* __restrict__ vw, const float* __restrict__ colsum,
    ushort* __restrict__ cvT)
{
    __shared__ float vs[128][68];
    const int t = threadIdx.x;
    const int b = blockIdx.x >> 4;
    const int k0 = (blockIdx.x & 15) * 128;
    #pragma unroll
    for (int i = 0; i < 8; ++i) {
        int idx = i * 256 + t;
        int r = idx >> 4, c4 = idx & 15;
        float4 v4 = *(const float4*)&vw[(size_t)(b * SS + k0 + r) * DD + c4 * 4];
        *(float4*)&vs[r][c4 * 4] = v4;
    }
    __syncthreads();
    const int tk = t & 127;
    const int tj = t >> 7;
    float c = 1.0f / sqrtf(colsum[b * SS + k0 + tk]);
    #pragma unroll
    for (int jj = 0; jj < 32; ++jj) {
        int j = jj * 2 + tj;
        cvT[((size_t)b * NCV + j) * SS + k0 + tk] = bf16rne(c * vs[tk][j]);
    }
    if (tj == 0) cvT[((size_t)b * NCV + 64) * SS + k0 + tk] = bf16rne(c);
}

// K4: 16 q-rows/block, 512 threads (8 waves); wave w owns k-range [256w, 256w+256).
// Barrier-free fused loop: QK^T MFMA -> score -> wave-private scT -> N-MFMA; then
// D reduce, N reduce (LDS atomics), out write, probs stream.
__global__ __launch_bounds__(512, 4) void k_final(
    const ushort* __restrict__ qh, const ushort* __restrict__ ql,
    const ushort* __restrict__ kh, const ushort* __restrict__ kl,
    const ushort* __restrict__ cvT,
    float* __restrict__ probs, float* __restrict__ out)
{
    __shared__ ushort scT[16 * SS];    // 64 KB, [q][k] bf16, byte ^= (q&7)<<4
    __shared__ float nred[16][64];     // 4 KB
    __shared__ float dPart[8][16];
    __shared__ float dInv[16];
    const int t = threadIdx.x;
    const int lane = t & 63;
    const int w = t >> 6;              // 0..7
    const int b = blockIdx.x >> 7;
    const int q0 = (blockIdx.x & 127) * 16;
    const int kbase = w * 256;

    if (t < 512) { ((float*)nred)[t] = 0.f; ((float*)nred)[t + 512] = 0.f; }

    bf16x8 ah[2], al[2];
    #pragma unroll
    for (int ks = 0; ks < 2; ++ks) {
        size_t off = (size_t)(b * SS + q0 + (lane & 15)) * DD + ks * 32 + (lane >> 4) * 8;
        ah[ks] = *(const bf16x8*)(qh + off);
        al[ks] = *(const bf16x8*)(ql + off);
    }
    const ushort* cbrow = cvT + ((size_t)b * NCV + 64) * SS;
    float dacc[4] = {0.f, 0.f, 0.f, 0.f};
    f32x4 nacc[4];
    #pragma unroll
    for (int ct = 0; ct < 4; ++ct) nacc[ct] = (f32x4){0.f, 0.f, 0.f, 0.f};

    const int qA = (lane >> 4) * 4;            // base q of my C-rows
    const int qB = lane & 15;                   // my A-frag row for N
    const int xorB = (qB & 7) << 4;

    #pragma unroll 2
    for (int kt2 = 0; kt2 < 8; ++kt2) {
        const int ks0 = kbase + kt2 * 32;
        const int kkA = ks0 + (lane & 15);
        const int kkB = kkA + 16;
        size_t roffA = (size_t)(b * SS + kkA) * DD + (lane >> 4) * 8;
        size_t roffB = (size_t)(b * SS + kkB) * DD + (lane >> 4) * 8;
        bf16x8 bhA0 = *(const bf16x8*)(kh + roffA);
        bf16x8 blA0 = *(const bf16x8*)(kl + roffA);
        bf16x8 bhA1 = *(const bf16x8*)(kh + roffA + 32);
        bf16x8 blA1 = *(const bf16x8*)(kl + roffA + 32);
        bf16x8 bhB0 = *(const bf16x8*)(kh + roffB);
        bf16x8 blB0 = *(const bf16x8*)(kl + roffB);
        bf16x8 bhB1 = *(const bf16x8*)(kh + roffB + 32);
        bf16x8 blB1 = *(const bf16x8*)(kl + roffB + 32);
        f32x4 aA = (f32x4){0.f,0.f,0.f,0.f}, aB = aA;
        aA = MFMA16(ah[0], bhA0, aA);  aB = MFMA16(ah[0], bhB0, aB);
        aA = MFMA16(ah[1], bhA1, aA);  aB = MFMA16(ah[1], bhB1, aB);
        aA = MFMA16(ah[0], blA0, aA);  aB = MFMA16(ah[0], blB0, aB);
        aA = MFMA16(ah[1], blA1, aA);  aB = MFMA16(ah[1], blB1, aB);
        aA = MFMA16(al[0], bhA0, aA);  aB = MFMA16(al[0], bhB0, aB);
        aA = MFMA16(al[1], bhA1, aA);  aB = MFMA16(al[1], bhB1, aB);
        float cbA = bf2f(cbrow[kkA]);
        float cbB = bf2f(cbrow[kkB]);
        const int kxA = kkA * 2, kxB = kkB * 2;
        #pragma unroll
        for (int r = 0; r < 4; ++r) {
            int q = qA + r;
            int xorv = (q & 7) << 4;
            float sA = score_fn(aA[r]);
            float sB = score_fn(aB[r]);
            ushort sbA = bf16rne(sA);
            ushort sbB = bf16rne(sB);
            *(ushort*)((char*)scT + q * 4096 + (kxA ^ xorv)) = sbA;
            *(ushort*)((char*)scT + q * 4096 + (kxB ^ xorv)) = sbB;
            dacc[r] = fmaf(bf2f(sbA), cbA, dacc[r]);
            dacc[r] = fmaf(bf2f(sbB), cbB, dacc[r]);
        }
        // N-accumulation over this 32-k slice (reads only this wave's writes)
        __builtin_amdgcn_s_waitcnt(0);   // lgkmcnt(0): own ds_writes complete
        int kb2 = (ks0 + (lane >> 4) * 8) * 2;
        bf16x8 af = *(bf16x8*)((char*)scT + qB * 4096 + (kb2 ^ xorB));
        #pragma unroll
        for (int ct = 0; ct < 4; ++ct) {
            bf16x8 bfv = *(const bf16x8*)(cvT + ((size_t)b * NCV + ct * 16 + (lane & 15)) * SS + ks0 + (lane >> 4) * 8);
            nacc[ct] = MFMA16(af, bfv, nacc[ct]);
        }
    }
    // D partial reduce (over lane&15 = k columns)
    #pragma unroll
    for (int r = 0; r < 4; ++r) {
        float d = dacc[r];
        d += __shfl_xor(d, 1, 64);
        d += __shfl_xor(d, 2, 64);
        d += __shfl_xor(d, 4, 64);
        d += __shfl_xor(d, 8, 64);
        if ((lane & 15) == 0) dPart[w][qA + r] = d;
    }
    __syncthreads();
    if (t < 16) dInv[t] = 1.0f / (dPart[0][t] + dPart[1][t] + dPart[2][t] + dPart[3][t]
                                + dPart[4][t] + dPart[5][t] + dPart[6][t] + dPart[7][t]);
    // cross-wave N reduce
    #pragma unroll
    for (int ct = 0; ct < 4; ++ct)
        #pragma unroll
        for (int r = 0; r < 4; ++r)
            atomicAdd(&nred[qA + r][ct * 16 + (lane & 15)], nacc[ct][r]);
    __syncthreads();
    // out write: 1024 values, 512 threads x 2
    {
        int q = t >> 5, col = (t & 31) * 2;
        float2 o;
        o.x = nred[q][col] * dInv[q];
        o.y = nred[q][col + 1] * dInv[q];
        *(float2*)&out[(size_t)(b * SS + q0 + q) * DD + col] = o;
    }
    // probs stream: wave w writes k in [kbase, kbase+256) for all 16 q
    #pragma unroll
    for (int qq = 0; qq < 8; ++qq) {
        const int q = qq * 2 + (lane >> 5);
        const float di = dInv[q];
        const int xorv = (q & 7) << 4;
        const int k = kbase + (lane & 31) * 8;
        bf16x8 sv = *(bf16x8*)((char*)scT + q * 4096 + ((k * 2) ^ xorv));
        bf16x8 cv8 = *(const bf16x8*)(cbrow + k);
        float4 o0, o1;
        o0.x = bf2f((ushort)sv[0]) * bf2f((ushort)cv8[0]) * di;
        o0.y = bf2f((ushort)sv[1]) * bf2f((ushort)cv8[1]) * di;
        o0.z = bf2f((ushort)sv[2]) * bf2f((ushort)cv8[2]) * di;
        o0.w = bf2f((ushort)sv[3]) * bf2f((ushort)cv8[3]) * di;
        o1.x = bf2f((ushort)sv[4]) * bf2f((ushort)cv8[4]) * di;
        o1.y = bf2f((ushort)sv[5]) * bf2f((ushort)cv8[5]) * di;
        o1.z = bf2f((ushort)sv[6]) * bf2f((ushort)cv8[6]) * di;
        o1.w = bf2f((ushort)sv[7]) * bf2f((ushort)cv8[7]) * di;
        size_t prow = (size_t)(b * SS + q0 + q) * SS;
        *(float4*)&probs[prow + k] = o0;
        *(float4*)&probs[prow + k + 4] = o1;
    }
}

extern "C" void kernel_launch(void* const* d_in, const int* in_sizes, int n_in,
                              void* d_out, int out_size, void* d_ws, size_t ws_size,
                              hipStream_t stream)
{
    const float* x  = (const float*)d_in[0];
    const float* Wq = (const float*)d_in[1];
    const float* bq = (const float*)d_in[2];
    const float* Wk = (const float*)d_in[3];
    const float* bk = (const float*)d_in[4];
    const float* Wv = (const float*)d_in[5];
    const float* bv = (const float*)d_in[6];

    float* out   = (float*)d_out;                       // [8,2048,64]
    float* probs = out + (size_t)BB * SS * DD;          // [8,2048,2048]

    const size_t NQ = (size_t)BB * SS * DD;             // 1,048,576
    ushort* qh    = (ushort*)d_ws;
    ushort* ql    = qh + NQ;
    ushort* kh    = ql + NQ;
    ushort* kl    = kh + NQ;
    float*  vw    = (float*)(kl + NQ);
    float*  colsum = vw + NQ;
    ushort* cvT   = (ushort*)(colsum + BB * SS);
    ushort* Whi   = cvT + (size_t)BB * NCV * SS;
    ushort* Wlo   = Whi + (size_t)192 * HH;
    float*  bcat  = (float*)(Wlo + (size_t)192 * HH);

    hipMemsetAsync(colsum, 0, BB * SS * sizeof(float), stream);
    k_prep  <<<192, 256, 0, stream>>>(Wq, Wk, Wv, bq, bk, bv, Whi, Wlo, bcat);
    k_projmm<<<512, 256, 0, stream>>>(x, Whi, Wlo, bcat, qh, ql, kh, kl, vw);
    k_colsum<<<2048, 256, 0, stream>>>(qh, ql, kh, kl, colsum);
    k_cvc   <<<128, 256, 0, stream>>>(vw, colsum, cvT);
    k_final <<<1024, 512, 0, stream>>>(qh, ql, kh, kl, cvT, probs, out);
}

// Round 5
// 271.606 us; speedup vs baseline: 1.0091x; 1.0091x over previous
//
#include <hip/hip_runtime.h>
#include <math.h>

#define BB 8
#define SS 2048
#define HH 1024
#define DD 64
#define NCV 65

typedef __attribute__((ext_vector_type(8))) short bf16x8;
typedef __attribute__((ext_vector_type(4))) float f32x4;

#define MFMA16(a, b, c) __builtin_amdgcn_mfma_f32_16x16x32_bf16(a, b, c, 0, 0, 0)

__device__ __forceinline__ ushort bf16rne(float f) {
    uint u = __float_as_uint(f);
    uint r = (u + 0x7FFFu + ((u >> 16) & 1u)) >> 16;
    return (ushort)r;
}
__device__ __forceinline__ float bf2f(ushort h) {
    return __uint_as_float(((uint)h) << 16);
}

// score = (1 + acos(clip(cos)))^-65.5
// acos via A&S 4.4.46: acos(x) = sqrt(1-x)*P(x), |err| <= ~3e-8 abs on [0,1].
__device__ __forceinline__ float score_fn(float cosv) {
    float ax = fminf(fabsf(cosv), 1.0f - 1e-7f);
    float p = fmaf(ax, -0.0012624911f, 0.0066700901f);
    p = fmaf(ax, p, -0.0170881256f);
    p = fmaf(ax, p, 0.0308918810f);
    p = fmaf(ax, p, -0.0501743046f);
    p = fmaf(ax, p, 0.0889789874f);
    p = fmaf(ax, p, -0.2145988016f);
    p = fmaf(ax, p, 1.5707963050f);
    float r = sqrtf(1.0f - ax) * p;                       // acos(|x|)
    float g = (cosv >= 0.0f) ? r : (3.14159265358979f - r);
    return exp2f(-65.5f * log2f(1.0f + g));
}

// K0: split W into bf16 hi/lo, layout Wcat[n][j], n = mat*64+d. Also bcat.
__global__ __launch_bounds__(256) void k_prep(
    const float* __restrict__ Wq, const float* __restrict__ Wk, const float* __restrict__ Wv,
    const float* __restrict__ bq, const float* __restrict__ bk, const float* __restrict__ bv,
    ushort* __restrict__ Whi, ushort* __restrict__ Wlo, float* __restrict__ bcat)
{
    const int n = blockIdx.x;          // 0..191
    const int m = n >> 6, d = n & 63;
    const float* W = (m == 0) ? Wq : (m == 1 ? Wk : Wv);
    #pragma unroll
    for (int i = 0; i < 4; ++i) {
        int j = i * 256 + threadIdx.x;
        float f = W[(size_t)j * DD + d];
        ushort h = bf16rne(f);
        Whi[(size_t)n * HH + j] = h;
        Wlo[(size_t)n * HH + j] = bf16rne(f - bf2f(h));
    }
    if (n == 0 && threadIdx.x < 192) {
        int t = threadIdx.x, mm = t >> 6, dd = t & 63;
        const float* b = (mm == 0) ? bq : (mm == 1 ? bk : bv);
        bcat[t] = b[dd];
    }
}

// K1: q,k,v = l2norm(x @ W + b) via split-bf16 MFMA.
__global__ __launch_bounds__(256) void k_projmm(
    const float* __restrict__ x, const ushort* __restrict__ Whi,
    const ushort* __restrict__ Wlo, const float* __restrict__ bcat,
    ushort* __restrict__ qh, ushort* __restrict__ ql,
    ushort* __restrict__ kh, ushort* __restrict__ kl,
    float* __restrict__ vw)
{
    __shared__ __align__(16) char smem[32 * 193 * 4];
    __shared__ float rns[96];
    __shared__ float bsh[192];
    ushort* xhi = (ushort*)smem;                 // [32][128] bf16, XOR-swizzled 16B units
    ushort* xlo = xhi + 32 * 128;
    float* ctile = (float*)smem;                 // [32][193] epilogue (aliases xhi/xlo)

    const int t = threadIdx.x;
    const int lane = t & 63;
    const int wid = t >> 6;
    const int row0 = blockIdx.x * 32;
    if (t < 192) bsh[t] = bcat[t];

    f32x4 acc[2][3];
    #pragma unroll
    for (int ar = 0; ar < 2; ++ar)
        #pragma unroll
        for (int bc = 0; bc < 3; ++bc)
            acc[ar][bc] = (f32x4){0.f, 0.f, 0.f, 0.f};

    for (int ch = 0; ch < 8; ++ch) {
        const int j0 = ch * 128;
        __syncthreads();
        #pragma unroll
        for (int i = 0; i < 2; ++i) {
            int u = i * 256 + t;
            int row = u >> 4, uc = u & 15;
            const float* xp = &x[(size_t)(row0 + row) * HH + j0 + uc * 8];
            float4 a = *(const float4*)xp;
            float4 b = *(const float4*)(xp + 4);
            float fs[8] = {a.x, a.y, a.z, a.w, b.x, b.y, b.z, b.w};
            bf16x8 hv, lv;
            #pragma unroll
            for (int e = 0; e < 8; ++e) {
                ushort h = bf16rne(fs[e]);
                hv[e] = (short)h;
                lv[e] = (short)bf16rne(fs[e] - bf2f(h));
            }
            int su = uc ^ (row & 7);
            *(bf16x8*)(xhi + row * 128 + su * 8) = hv;
            *(bf16x8*)(xlo + row * 128 + su * 8) = lv;
        }
        __syncthreads();
        #pragma unroll
        for (int ks = 0; ks < 4; ++ks) {
            bf16x8 ah[2], al[2], bh[3], bl[3];
            #pragma unroll
            for (int ar = 0; ar < 2; ++ar) {
                int row = ar * 16 + (lane & 15);
                int su = (ks * 4 + (lane >> 4)) ^ (row & 7);
                ah[ar] = *(const bf16x8*)(xhi + row * 128 + su * 8);
                al[ar] = *(const bf16x8*)(xlo + row * 128 + su * 8);
            }
            const int koff = j0 + ks * 32 + (lane >> 4) * 8;
            #pragma unroll
            for (int bc = 0; bc < 3; ++bc) {
                int n = wid * 48 + bc * 16 + (lane & 15);
                bh[bc] = *(const bf16x8*)(Whi + (size_t)n * HH + koff);
                bl[bc] = *(const bf16x8*)(Wlo + (size_t)n * HH + koff);
            }
            #pragma unroll
            for (int ar = 0; ar < 2; ++ar)
                #pragma unroll
                for (int bc = 0; bc < 3; ++bc) {
                    acc[ar][bc] = MFMA16(ah[ar], bh[bc], acc[ar][bc]);
                    acc[ar][bc] = MFMA16(ah[ar], bl[bc], acc[ar][bc]);
                    acc[ar][bc] = MFMA16(al[ar], bh[bc], acc[ar][bc]);
                }
        }
    }
    __syncthreads();
    #pragma unroll
    for (int ar = 0; ar < 2; ++ar)
        #pragma unroll
        for (int bc = 0; bc < 3; ++bc) {
            int n = wid * 48 + bc * 16 + (lane & 15);
            #pragma unroll
            for (int r = 0; r < 4; ++r) {
                int row = ar * 16 + (lane >> 4) * 4 + r;
                ctile[row * 193 + n] = acc[ar][bc][r];
            }
        }
    __syncthreads();
    if (t < 96) {
        int mat = t >> 5, row = t & 31;
        float ss = 0.f;
        #pragma unroll 8
        for (int d = 0; d < 64; ++d) {
            float v = ctile[row * 193 + mat * 64 + d] + bsh[mat * 64 + d];
            ss = fmaf(v, v, ss);
        }
        rns[t] = 1.0f / fmaxf(sqrtf(ss), 1e-12f);
    }
    __syncthreads();
    #pragma unroll
    for (int i = 0; i < 24; ++i) {
        int idx = i * 256 + t;
        int row = idx / 192;
        int n = idx - row * 192;
        float v = (ctile[row * 193 + n] + bsh[n]) * rns[(n >> 6) * 32 + row];
        size_t off = (size_t)(row0 + row) * DD + (n & 63);
        if (n < 64) {
            ushort h = bf16rne(v);
            qh[off] = h; ql[off] = bf16rne(v - bf2f(h));
        } else if (n < 128) {
            ushort h = bf16rne(v);
            kh[off] = h; kl[off] = bf16rne(v - bf2f(h));
        } else {
            vw[off] = v;
        }
    }
}

// K2: colsum[b][k] = sum_q score(q,k).
// Grid = 8b * 64qt(32 rows) * 4ks = 2048 blocks, 256 threads.
__global__ __launch_bounds__(256) void k_colsum(
    const ushort* __restrict__ qh, const ushort* __restrict__ ql,
    const ushort* __restrict__ kh, const ushort* __restrict__ kl,
    float* __restrict__ colsum)
{
    const int t = threadIdx.x;
    const int lane = t & 63;
    const int w = t >> 6;
    const int bid = blockIdx.x;
    const int b  = bid >> 8;
    const int q0 = ((bid >> 2) & 63) * 32;
    const int kbase = (bid & 3) * 512 + w * 128;

    bf16x8 ah[2][2], al[2][2];
    #pragma unroll
    for (int rt = 0; rt < 2; ++rt)
        #pragma unroll
        for (int ks = 0; ks < 2; ++ks) {
            size_t off = (size_t)(b * SS + q0 + rt * 16 + (lane & 15)) * DD + ks * 32 + (lane >> 4) * 8;
            ah[rt][ks] = *(const bf16x8*)(qh + off);
            al[rt][ks] = *(const bf16x8*)(ql + off);
        }

    #pragma unroll
    for (int kt2 = 0; kt2 < 4; ++kt2) {
        const int kkA = kbase + kt2 * 32 + (lane & 15);
        const int kkB = kkA + 16;
        size_t roffA = (size_t)(b * SS + kkA) * DD + (lane >> 4) * 8;
        size_t roffB = (size_t)(b * SS + kkB) * DD + (lane >> 4) * 8;
        bf16x8 bhA0 = *(const bf16x8*)(kh + roffA);
        bf16x8 blA0 = *(const bf16x8*)(kl + roffA);
        bf16x8 bhA1 = *(const bf16x8*)(kh + roffA + 32);
        bf16x8 blA1 = *(const bf16x8*)(kl + roffA + 32);
        bf16x8 bhB0 = *(const bf16x8*)(kh + roffB);
        bf16x8 blB0 = *(const bf16x8*)(kl + roffB);
        bf16x8 bhB1 = *(const bf16x8*)(kh + roffB + 32);
        bf16x8 blB1 = *(const bf16x8*)(kl + roffB + 32);
        f32x4 a0A = (f32x4){0.f,0.f,0.f,0.f}, a1A = a0A, a0B = a0A, a1B = a0A;
        a0A = MFMA16(ah[0][0], bhA0, a0A); a1A = MFMA16(ah[1][0], bhA0, a1A);
        a0B = MFMA16(ah[0][0], bhB0, a0B); a1B = MFMA16(ah[1][0], bhB0, a1B);
        a0A = MFMA16(ah[0][1], bhA1, a0A); a1A = MFMA16(ah[1][1], bhA1, a1A);
        a0B = MFMA16(ah[0][1], bhB1, a0B); a1B = MFMA16(ah[1][1], bhB1, a1B);
        a0A = MFMA16(ah[0][0], blA0, a0A); a1A = MFMA16(ah[1][0], blA0, a1A);
        a0B = MFMA16(ah[0][0], blB0, a0B); a1B = MFMA16(ah[1][0], blB0, a1B);
        a0A = MFMA16(ah[0][1], blA1, a0A); a1A = MFMA16(ah[1][1], blA1, a1A);
        a0B = MFMA16(ah[0][1], blB1, a0B); a1B = MFMA16(ah[1][1], blB1, a1B);
        a0A = MFMA16(al[0][0], bhA0, a0A); a1A = MFMA16(al[1][0], bhA0, a1A);
        a0B = MFMA16(al[0][0], bhB0, a0B); a1B = MFMA16(al[1][0], bhB0, a1B);
        a0A = MFMA16(al[0][1], bhA1, a0A); a1A = MFMA16(al[1][1], bhA1, a1A);
        a0B = MFMA16(al[0][1], bhB1, a0B); a1B = MFMA16(al[1][1], bhB1, a1B);
        float sA = 0.f, sB = 0.f;
        #pragma unroll
        for (int r = 0; r < 4; ++r) {
            sA += score_fn(a0A[r]); sA += score_fn(a1A[r]);
            sB += score_fn(a0B[r]); sB += score_fn(a1B[r]);
        }
        sA += __shfl_xor(sA, 16, 64); sA += __shfl_xor(sA, 32, 64);
        sB += __shfl_xor(sB, 16, 64); sB += __shfl_xor(sB, 32, 64);
        if (lane < 16) {
            atomicAdd(&colsum[b * SS + kkA], sA);
            atomicAdd(&colsum[b * SS + kkB], sB);
        }
    }
}

// K3: c = colsum^-0.5; cvT[b][j][k] = bf16(c*v[k][j]) for j<64, row 64 = bf16(c).
__global__ __launch_bounds__(256) void k_cvc(
    const float* __restrict__ vw, const float* __restrict__ colsum,
    ushort* __restrict__ cvT)
{
    __shared__ float vs[128][68];
    const int t = threadIdx.x;
    const int b = blockIdx.x >> 4;
    const int k0 = (blockIdx.x & 15) * 128;
    #pragma unroll
    for (int i = 0; i < 8; ++i) {
        int idx = i * 256 + t;
        int r = idx >> 4, c4 = idx & 15;
        float4 v4 = *(const float4*)&vw[(size_t)(b * SS + k0 + r) * DD + c4 * 4];
        *(float4*)&vs[r][c4 * 4] = v4;
    }
    __syncthreads();
    const int tk = t & 127;
    const int tj = t >> 7;
    float c = 1.0f / sqrtf(colsum[b * SS + k0 + tk]);
    #pragma unroll
    for (int jj = 0; jj < 32; ++jj) {
        int j = jj * 2 + tj;
        cvT[((size_t)b * NCV + j) * SS + k0 + tk] = bf16rne(c * vs[tk][j]);
    }
    if (tj == 0) cvT[((size_t)b * NCV + 64) * SS + k0 + tk] = bf16rne(c);
}

// K4: 16 q-rows/block, 512 threads (8 waves); wave w owns k-range [256w, 256w+256).
// Swapped QK^T: mfma(A=K rows, B=Q rows) -> C[col=q][row=k]; lane's 4 scores are
// 4 consecutive k for one q -> packed ds_write_b64. lgkm-only wait keeps global
// loads in flight. Then D reduce, N cross-wave reduce, out + probs.
__global__ __launch_bounds__(512, 4) void k_final(
    const ushort* __restrict__ qh, const ushort* __restrict__ ql,
    const ushort* __restrict__ kh, const ushort* __restrict__ kl,
    const ushort* __restrict__ cvT,
    float* __restrict__ probs, float* __restrict__ out)
{
    __shared__ ushort scT[16 * SS];    // 64 KB, [q][k] bf16, byte ^= (q&15)<<4
    __shared__ float nred[16][64];     // 4 KB
    __shared__ float dPart[8][16];
    __shared__ float dInv[16];
    const int t = threadIdx.x;
    const int lane = t & 63;
    const int w = t >> 6;              // 0..7
    const int b = blockIdx.x >> 7;
    const int q0 = (blockIdx.x & 127) * 16;
    const int kbase = w * 256;
    const int g = lane >> 4;           // 0..3
    const int qn = lane & 15;          // q col (QK^T C) and A-row q (N MFMA)
    const int xorq = qn << 4;

    ((float*)nred)[t] = 0.f;
    ((float*)nred)[t + 512] = 0.f;

    // Q B-frags (same lane mapping as A-frags -> same addresses as before)
    bf16x8 qbh[2], qbl[2];
    #pragma unroll
    for (int ks = 0; ks < 2; ++ks) {
        size_t off = (size_t)(b * SS + q0 + qn) * DD + ks * 32 + g * 8;
        qbh[ks] = *(const bf16x8*)(qh + off);
        qbl[ks] = *(const bf16x8*)(ql + off);
    }
    const ushort* cbrow = cvT + ((size_t)b * NCV + 64) * SS;
    float dacc = 0.f;
    f32x4 nacc[4];
    #pragma unroll
    for (int ct = 0; ct < 4; ++ct) nacc[ct] = (f32x4){0.f, 0.f, 0.f, 0.f};

    #pragma unroll 2
    for (int kt = 0; kt < 8; ++kt) {
        const int ks0 = kbase + kt * 32;
        const int kkA = ks0 + qn;                       // tile0 K row
        size_t roffA = (size_t)(b * SS + kkA) * DD + g * 8;
        size_t roffB = roffA + (size_t)16 * DD;         // tile1 K row (+16)
        bf16x8 kah0 = *(const bf16x8*)(kh + roffA);
        bf16x8 kal0 = *(const bf16x8*)(kl + roffA);
        bf16x8 kah1 = *(const bf16x8*)(kh + roffA + 32);
        bf16x8 kal1 = *(const bf16x8*)(kl + roffA + 32);
        bf16x8 kbh0 = *(const bf16x8*)(kh + roffB);
        bf16x8 kbl0 = *(const bf16x8*)(kl + roffB);
        bf16x8 kbh1 = *(const bf16x8*)(kh + roffB + 32);
        bf16x8 kbl1 = *(const bf16x8*)(kl + roffB + 32);
        f32x4 aT0 = (f32x4){0.f,0.f,0.f,0.f}, aT1 = aT0;
        aT0 = MFMA16(kah0, qbh[0], aT0);  aT1 = MFMA16(kbh0, qbh[0], aT1);
        aT0 = MFMA16(kah1, qbh[1], aT0);  aT1 = MFMA16(kbh1, qbh[1], aT1);
        aT0 = MFMA16(kah0, qbl[0], aT0);  aT1 = MFMA16(kbh0, qbl[0], aT1);
        aT0 = MFMA16(kah1, qbl[1], aT0);  aT1 = MFMA16(kbh1, qbl[1], aT1);
        aT0 = MFMA16(kal0, qbh[0], aT0);  aT1 = MFMA16(kbl0, qbh[0], aT1);
        aT0 = MFMA16(kal1, qbh[1], aT0);  aT1 = MFMA16(kbl1, qbh[1], aT1);

        const int kc0 = ks0 + g * 4;                    // my 4-k base, tile0
        uint2 cp0 = *(const uint2*)(cbrow + kc0);
        uint2 cp1 = *(const uint2*)(cbrow + kc0 + 16);

        ushort s0 = bf16rne(score_fn(aT0[0]));
        ushort s1 = bf16rne(score_fn(aT0[1]));
        ushort s2 = bf16rne(score_fn(aT0[2]));
        ushort s3 = bf16rne(score_fn(aT0[3]));
        dacc = fmaf(bf2f(s0), bf2f((ushort)(cp0.x & 0xFFFFu)), dacc);
        dacc = fmaf(bf2f(s1), bf2f((ushort)(cp0.x >> 16)), dacc);
        dacc = fmaf(bf2f(s2), bf2f((ushort)(cp0.y & 0xFFFFu)), dacc);
        dacc = fmaf(bf2f(s3), bf2f((ushort)(cp0.y >> 16)), dacc);
        uint2 wv0;
        wv0.x = (uint)s0 | ((uint)s1 << 16);
        wv0.y = (uint)s2 | ((uint)s3 << 16);
        *(uint2*)((char*)scT + qn * 4096 + ((kc0 * 2) ^ xorq)) = wv0;

        ushort u0 = bf16rne(score_fn(aT1[0]));
        ushort u1 = bf16rne(score_fn(aT1[1]));
        ushort u2 = bf16rne(score_fn(aT1[2]));
        ushort u3 = bf16rne(score_fn(aT1[3]));
        dacc = fmaf(bf2f(u0), bf2f((ushort)(cp1.x & 0xFFFFu)), dacc);
        dacc = fmaf(bf2f(u1), bf2f((ushort)(cp1.x >> 16)), dacc);
        dacc = fmaf(bf2f(u2), bf2f((ushort)(cp1.y & 0xFFFFu)), dacc);
        dacc = fmaf(bf2f(u3), bf2f((ushort)(cp1.y >> 16)), dacc);
        uint2 wv1;
        wv1.x = (uint)u0 | ((uint)u1 << 16);
        wv1.y = (uint)u2 | ((uint)u3 << 16);
        *(uint2*)((char*)scT + qn * 4096 + (((kc0 + 16) * 2) ^ xorq)) = wv1;

        // wait only for own ds_writes; keep global loads in flight
        asm volatile("s_waitcnt lgkmcnt(0)" ::: "memory");
        __builtin_amdgcn_sched_barrier(0);
        bf16x8 af = *(const bf16x8*)((char*)scT + qn * 4096 + (((ks0 + g * 8) * 2) ^ xorq));
        #pragma unroll
        for (int ct = 0; ct < 4; ++ct) {
            bf16x8 bfv = *(const bf16x8*)(cvT + ((size_t)b * NCV + ct * 16 + qn) * SS + ks0 + g * 8);
            nacc[ct] = MFMA16(af, bfv, nacc[ct]);
        }
    }
    // D: dacc covers q=qn over this wave's 256 k (split across g-groups)
    {
        float d = dacc;
        d += __shfl_xor(d, 16, 64);
        d += __shfl_xor(d, 32, 64);
        if (lane < 16) dPart[w][lane] = d;
    }
    __syncthreads();
    if (t < 16) dInv[t] = 1.0f / (dPart[0][t] + dPart[1][t] + dPart[2][t] + dPart[3][t]
                                + dPart[4][t] + dPart[5][t] + dPart[6][t] + dPart[7][t]);
    // cross-wave N reduce: nacc C-layout col=d(qn), row=(g*4+r)=q
    #pragma unroll
    for (int ct = 0; ct < 4; ++ct)
        #pragma unroll
        for (int r = 0; r < 4; ++r)
            atomicAdd(&nred[g * 4 + r][ct * 16 + qn], nacc[ct][r]);
    __syncthreads();
    // out write: 1024 values, 512 threads x 2
    {
        int q = t >> 5, col = (t & 31) * 2;
        float2 o;
        o.x = nred[q][col] * dInv[q];
        o.y = nred[q][col + 1] * dInv[q];
        *(float2*)&out[(size_t)(b * SS + q0 + q) * DD + col] = o;
    }
    // probs stream: wave w writes k in [kbase, kbase+256) for all 16 q
    #pragma unroll
    for (int qq = 0; qq < 8; ++qq) {
        const int q = qq * 2 + (lane >> 5);
        const float di = dInv[q];
        const int xorv = q << 4;
        const int k = kbase + (lane & 31) * 8;
        bf16x8 sv = *(bf16x8*)((char*)scT + q * 4096 + ((k * 2) ^ xorv));
        bf16x8 cv8 = *(const bf16x8*)(cbrow + k);
        float4 o0, o1;
        o0.x = bf2f((ushort)sv[0]) * bf2f((ushort)cv8[0]) * di;
        o0.y = bf2f((ushort)sv[1]) * bf2f((ushort)cv8[1]) * di;
        o0.z = bf2f((ushort)sv[2]) * bf2f((ushort)cv8[2]) * di;
        o0.w = bf2f((ushort)sv[3]) * bf2f((ushort)cv8[3]) * di;
        o1.x = bf2f((ushort)sv[4]) * bf2f((ushort)cv8[4]) * di;
        o1.y = bf2f((ushort)sv[5]) * bf2f((ushort)cv8[5]) * di;
        o1.z = bf2f((ushort)sv[6]) * bf2f((ushort)cv8[6]) * di;
        o1.w = bf2f((ushort)sv[7]) * bf2f((ushort)cv8[7]) * di;
        size_t prow = (size_t)(b * SS + q0 + q) * SS;
        *(float4*)&probs[prow + k] = o0;
        *(float4*)&probs[prow + k + 4] = o1;
    }
}

extern "C" void kernel_launch(void* const* d_in, const int* in_sizes, int n_in,
                              void* d_out, int out_size, void* d_ws, size_t ws_size,
                              hipStream_t stream)
{
    const float* x  = (const float*)d_in[0];
    const float* Wq = (const float*)d_in[1];
    const float* bq = (const float*)d_in[2];
    const float* Wk = (const float*)d_in[3];
    const float* bk = (const float*)d_in[4];
    const float* Wv = (const float*)d_in[5];
    const float* bv = (const float*)d_in[6];

    float* out   = (float*)d_out;                       // [8,2048,64]
    float* probs = out + (size_t)BB * SS * DD;          // [8,2048,2048]

    const size_t NQ = (size_t)BB * SS * DD;             // 1,048,576
    ushort* qh    = (ushort*)d_ws;
    ushort* ql    = qh + NQ;
    ushort* kh    = ql + NQ;
    ushort* kl    = kh + NQ;
    float*  vw    = (float*)(kl + NQ);
    float*  colsum = vw + NQ;
    ushort* cvT   = (ushort*)(colsum + BB * SS);
    ushort* Whi   = cvT + (size_t)BB * NCV * SS;
    ushort* Wlo   = Whi + (size_t)192 * HH;
    float*  bcat  = (float*)(Wlo + (size_t)192 * HH);

    hipMemsetAsync(colsum, 0, BB * SS * sizeof(float), stream);
    k_prep  <<<192, 256, 0, stream>>>(Wq, Wk, Wv, bq, bk, bv, Whi, Wlo, bcat);
    k_projmm<<<512, 256, 0, stream>>>(x, Whi, Wlo, bcat, qh, ql, kh, kl, vw);
    k_colsum<<<2048, 256, 0, stream>>>(qh, ql, kh, kl, colsum);
    k_cvc   <<<128, 256, 0, stream>>>(vw, colsum, cvT);
    k_final <<<1024, 512, 0, stream>>>(qh, ql, kh, kl, cvT, probs, out);
}

// Round 6
// 223.230 us; speedup vs baseline: 1.2278x; 1.2167x over previous
//
#include <hip/hip_runtime.h>
#include <math.h>

#define BB 8
#define SS 2048
#define HH 1024
#define DD 64
#define NCV 65

typedef __attribute__((ext_vector_type(8))) short bf16x8;
typedef __attribute__((ext_vector_type(4))) float f32x4;

#define MFMA16(a, b, c) __builtin_amdgcn_mfma_f32_16x16x32_bf16(a, b, c, 0, 0, 0)

__device__ __forceinline__ ushort bf16rne(float f) {
    uint u = __float_as_uint(f);
    uint r = (u + 0x7FFFu + ((u >> 16) & 1u)) >> 16;
    return (ushort)r;
}
__device__ __forceinline__ float bf2f(ushort h) {
    return __uint_as_float(((uint)h) << 16);
}

// score = (1 + acos(clip(cos)))^-65.5
__device__ __forceinline__ float score_fn(float cosv) {
    float ax = fminf(fabsf(cosv), 1.0f - 1e-7f);
    float p = fmaf(ax, -0.0012624911f, 0.0066700901f);
    p = fmaf(ax, p, -0.0170881256f);
    p = fmaf(ax, p, 0.0308918810f);
    p = fmaf(ax, p, -0.0501743046f);
    p = fmaf(ax, p, 0.0889789874f);
    p = fmaf(ax, p, -0.2145988016f);
    p = fmaf(ax, p, 1.5707963050f);
    float r = sqrtf(1.0f - ax) * p;                       // acos(|x|)
    float g = (cosv >= 0.0f) ? r : (3.14159265358979f - r);
    return exp2f(-65.5f * log2f(1.0f + g));
}

// K0: split W into bf16 hi/lo, layout Wcat[n][j], n = mat*64+d. Also bcat.
__global__ __launch_bounds__(256) void k_prep(
    const float* __restrict__ Wq, const float* __restrict__ Wk, const float* __restrict__ Wv,
    const float* __restrict__ bq, const float* __restrict__ bk, const float* __restrict__ bv,
    ushort* __restrict__ Whi, ushort* __restrict__ Wlo, float* __restrict__ bcat)
{
    const int n = blockIdx.x;          // 0..191
    const int m = n >> 6, d = n & 63;
    const float* W = (m == 0) ? Wq : (m == 1 ? Wk : Wv);
    #pragma unroll
    for (int i = 0; i < 4; ++i) {
        int j = i * 256 + threadIdx.x;
        float f = W[(size_t)j * DD + d];
        ushort h = bf16rne(f);
        Whi[(size_t)n * HH + j] = h;
        Wlo[(size_t)n * HH + j] = bf16rne(f - bf2f(h));
    }
    if (n == 0 && threadIdx.x < 192) {
        int t = threadIdx.x, mm = t >> 6, dd = t & 63;
        const float* b = (mm == 0) ? bq : (mm == 1 ? bk : bv);
        bcat[t] = b[dd];
    }
}

// K1: q,k,v = l2norm(x @ W + b) via split-bf16 MFMA.
__global__ __launch_bounds__(256) void k_projmm(
    const float* __restrict__ x, const ushort* __restrict__ Whi,
    const ushort* __restrict__ Wlo, const float* __restrict__ bcat,
    ushort* __restrict__ qh, ushort* __restrict__ ql,
    ushort* __restrict__ kh, ushort* __restrict__ kl,
    float* __restrict__ vw)
{
    __shared__ __align__(16) char smem[32 * 193 * 4];
    __shared__ float rns[96];
    __shared__ float bsh[192];
    ushort* xhi = (ushort*)smem;                 // [32][128] bf16, XOR-swizzled 16B units
    ushort* xlo = xhi + 32 * 128;
    float* ctile = (float*)smem;                 // [32][193] epilogue (aliases xhi/xlo)

    const int t = threadIdx.x;
    const int lane = t & 63;
    const int wid = t >> 6;
    const int row0 = blockIdx.x * 32;
    if (t < 192) bsh[t] = bcat[t];

    f32x4 acc[2][3];
    #pragma unroll
    for (int ar = 0; ar < 2; ++ar)
        #pragma unroll
        for (int bc = 0; bc < 3; ++bc)
            acc[ar][bc] = (f32x4){0.f, 0.f, 0.f, 0.f};

    for (int ch = 0; ch < 8; ++ch) {
        const int j0 = ch * 128;
        __syncthreads();
        #pragma unroll
        for (int i = 0; i < 2; ++i) {
            int u = i * 256 + t;
            int row = u >> 4, uc = u & 15;
            const float* xp = &x[(size_t)(row0 + row) * HH + j0 + uc * 8];
            float4 a = *(const float4*)xp;
            float4 b = *(const float4*)(xp + 4);
            float fs[8] = {a.x, a.y, a.z, a.w, b.x, b.y, b.z, b.w};
            bf16x8 hv, lv;
            #pragma unroll
            for (int e = 0; e < 8; ++e) {
                ushort h = bf16rne(fs[e]);
                hv[e] = (short)h;
                lv[e] = (short)bf16rne(fs[e] - bf2f(h));
            }
            int su = uc ^ (row & 7);
            *(bf16x8*)(xhi + row * 128 + su * 8) = hv;
            *(bf16x8*)(xlo + row * 128 + su * 8) = lv;
        }
        __syncthreads();
        #pragma unroll
        for (int ks = 0; ks < 4; ++ks) {
            bf16x8 ah[2], al[2], bh[3], bl[3];
            #pragma unroll
            for (int ar = 0; ar < 2; ++ar) {
                int row = ar * 16 + (lane & 15);
                int su = (ks * 4 + (lane >> 4)) ^ (row & 7);
                ah[ar] = *(const bf16x8*)(xhi + row * 128 + su * 8);
                al[ar] = *(const bf16x8*)(xlo + row * 128 + su * 8);
            }
            const int koff = j0 + ks * 32 + (lane >> 4) * 8;
            #pragma unroll
            for (int bc = 0; bc < 3; ++bc) {
                int n = wid * 48 + bc * 16 + (lane & 15);
                bh[bc] = *(const bf16x8*)(Whi + (size_t)n * HH + koff);
                bl[bc] = *(const bf16x8*)(Wlo + (size_t)n * HH + koff);
            }
            #pragma unroll
            for (int ar = 0; ar < 2; ++ar)
                #pragma unroll
                for (int bc = 0; bc < 3; ++bc) {
                    acc[ar][bc] = MFMA16(ah[ar], bh[bc], acc[ar][bc]);
                    acc[ar][bc] = MFMA16(ah[ar], bl[bc], acc[ar][bc]);
                    acc[ar][bc] = MFMA16(al[ar], bh[bc], acc[ar][bc]);
                }
        }
    }
    __syncthreads();
    #pragma unroll
    for (int ar = 0; ar < 2; ++ar)
        #pragma unroll
        for (int bc = 0; bc < 3; ++bc) {
            int n = wid * 48 + bc * 16 + (lane & 15);
            #pragma unroll
            for (int r = 0; r < 4; ++r) {
                int row = ar * 16 + (lane >> 4) * 4 + r;
                ctile[row * 193 + n] = acc[ar][bc][r];
            }
        }
    __syncthreads();
    if (t < 96) {
        int mat = t >> 5, row = t & 31;
        float ss = 0.f;
        #pragma unroll 8
        for (int d = 0; d < 64; ++d) {
            float v = ctile[row * 193 + mat * 64 + d] + bsh[mat * 64 + d];
            ss = fmaf(v, v, ss);
        }
        rns[t] = 1.0f / fmaxf(sqrtf(ss), 1e-12f);
    }
    __syncthreads();
    #pragma unroll
    for (int i = 0; i < 24; ++i) {
        int idx = i * 256 + t;
        int row = idx / 192;
        int n = idx - row * 192;
        float v = (ctile[row * 193 + n] + bsh[n]) * rns[(n >> 6) * 32 + row];
        size_t off = (size_t)(row0 + row) * DD + (n & 63);
        if (n < 64) {
            ushort h = bf16rne(v);
            qh[off] = h; ql[off] = bf16rne(v - bf2f(h));
        } else if (n < 128) {
            ushort h = bf16rne(v);
            kh[off] = h; kl[off] = bf16rne(v - bf2f(h));
        } else {
            vw[off] = v;
        }
    }
}

// K2: score(q,k) once -> bf16, stored in upper half of each probs row.
// Row r=(b*2048+q): score bf16 at ushort offset r*4096 + 2048 + k.
// Grid = 8b * 128qt * 2ks = 2048 blocks, 256 thr. Wave w: k in [ks*1024+w*256, +256).
// Swapped QK^T (A=K rows, B=Q cols): lane (g,qn) reg r = score[k=tile+g*4+r][q=qn].
__global__ __launch_bounds__(256, 4) void k_score(
    const ushort* __restrict__ qh, const ushort* __restrict__ ql,
    const ushort* __restrict__ kh, const ushort* __restrict__ kl,
    ushort* __restrict__ scrS)
{
    const int t = threadIdx.x;
    const int lane = t & 63;
    const int w = t >> 6;
    const int bid = blockIdx.x;
    const int b  = bid >> 8;
    const int q0 = ((bid >> 1) & 127) * 16;
    const int kbase = (bid & 1) * 1024 + w * 256;
    const int qn = lane & 15;
    const int g = lane >> 4;

    bf16x8 qbh[2], qbl[2];
    #pragma unroll
    for (int ks = 0; ks < 2; ++ks) {
        size_t off = (size_t)(b * SS + q0 + qn) * DD + ks * 32 + g * 8;
        qbh[ks] = *(const bf16x8*)(qh + off);
        qbl[ks] = *(const bf16x8*)(ql + off);
    }
    ushort* srow = scrS + (size_t)(b * SS + q0 + qn) * 4096 + 2048;

    #pragma unroll 2
    for (int kt = 0; kt < 8; ++kt) {
        const int ks0 = kbase + kt * 32;
        size_t roffA = (size_t)(b * SS + ks0 + qn) * DD + g * 8;
        size_t roffB = roffA + (size_t)16 * DD;
        bf16x8 kah0 = *(const bf16x8*)(kh + roffA);
        bf16x8 kal0 = *(const bf16x8*)(kl + roffA);
        bf16x8 kah1 = *(const bf16x8*)(kh + roffA + 32);
        bf16x8 kal1 = *(const bf16x8*)(kl + roffA + 32);
        bf16x8 kbh0 = *(const bf16x8*)(kh + roffB);
        bf16x8 kbl0 = *(const bf16x8*)(kl + roffB);
        bf16x8 kbh1 = *(const bf16x8*)(kh + roffB + 32);
        bf16x8 kbl1 = *(const bf16x8*)(kl + roffB + 32);
        f32x4 aT0 = (f32x4){0.f, 0.f, 0.f, 0.f}, aT1 = aT0;
        aT0 = MFMA16(kah0, qbh[0], aT0);  aT1 = MFMA16(kbh0, qbh[0], aT1);
        aT0 = MFMA16(kah1, qbh[1], aT0);  aT1 = MFMA16(kbh1, qbh[1], aT1);
        aT0 = MFMA16(kah0, qbl[0], aT0);  aT1 = MFMA16(kbh0, qbl[0], aT1);
        aT0 = MFMA16(kah1, qbl[1], aT0);  aT1 = MFMA16(kbh1, qbl[1], aT1);
        aT0 = MFMA16(kal0, qbh[0], aT0);  aT1 = MFMA16(kbl0, qbh[0], aT1);
        aT0 = MFMA16(kal1, qbh[1], aT0);  aT1 = MFMA16(kbl1, qbh[1], aT1);

        const int kc0 = ks0 + g * 4;
        uint2 wv0, wv1;
        wv0.x = (uint)bf16rne(score_fn(aT0[0])) | ((uint)bf16rne(score_fn(aT0[1])) << 16);
        wv0.y = (uint)bf16rne(score_fn(aT0[2])) | ((uint)bf16rne(score_fn(aT0[3])) << 16);
        wv1.x = (uint)bf16rne(score_fn(aT1[0])) | ((uint)bf16rne(score_fn(aT1[1])) << 16);
        wv1.y = (uint)bf16rne(score_fn(aT1[2])) | ((uint)bf16rne(score_fn(aT1[3])) << 16);
        *(uint2*)(srow + kc0) = wv0;
        *(uint2*)(srow + kc0 + 16) = wv1;
    }
}

// K3: colsum over q (streaming) -> c = colsum^-0.5 (in-block) -> cvT build.
// Grid = 8b * 32 (k-chunks of 64) = 256 blocks, 256 thr.
__global__ __launch_bounds__(256) void k_csum_cvc(
    const ushort* __restrict__ scrS, const float* __restrict__ vw,
    ushort* __restrict__ cvT)
{
    __shared__ float cls[32][64];      // 8 KB
    __shared__ float csh[64];
    __shared__ float vsT[64][65];      // 16.6 KB [j][kk]
    const int t = threadIdx.x;
    const int b = blockIdx.x >> 5;
    const int k0 = (blockIdx.x & 31) * 64;

    // phase 1: column partial sums. tq = t>>3 (32 q-par), tk = t&7 (8 k-groups of 8)
    {
        const int tq = t >> 3, tk = t & 7;
        float colacc[8];
        #pragma unroll
        for (int e = 0; e < 8; ++e) colacc[e] = 0.f;
        #pragma unroll 4
        for (int it = 0; it < 64; ++it) {
            int q = it * 32 + tq;
            bf16x8 s8 = *(const bf16x8*)(scrS + (size_t)(b * SS + q) * 4096 + 2048 + k0 + tk * 8);
            #pragma unroll
            for (int e = 0; e < 8; ++e) colacc[e] += bf2f((ushort)s8[e]);
        }
        #pragma unroll
        for (int e = 0; e < 8; ++e) cls[tq][tk * 8 + e] = colacc[e];
    }
    __syncthreads();
    if (t < 64) {
        float s = 0.f;
        #pragma unroll
        for (int tq = 0; tq < 32; ++tq) s += cls[tq][t];
        csh[t] = 1.0f / sqrtf(s);
    }
    // phase 2: stage v^T: rows k0..k0+64, all 64 j
    {
        const int j = t & 63, rr = t >> 6;
        #pragma unroll
        for (int it = 0; it < 16; ++it) {
            int kk = it * 4 + rr;
            vsT[j][kk] = vw[(size_t)(b * SS + k0 + kk) * DD + j];
        }
    }
    __syncthreads();
    // phase 3: cvT[j][k0+kk] = bf16(c[kk]*v[kk][j]); row 64 = bf16(c)
    {
        const int kk4 = (t & 15) * 4;
        #pragma unroll
        for (int jt = 0; jt < 4; ++jt) {
            int j = jt * 16 + (t >> 4);
            uint2 wv;
            wv.x = (uint)bf16rne(csh[kk4 + 0] * vsT[j][kk4 + 0])
                 | ((uint)bf16rne(csh[kk4 + 1] * vsT[j][kk4 + 1]) << 16);
            wv.y = (uint)bf16rne(csh[kk4 + 2] * vsT[j][kk4 + 2])
                 | ((uint)bf16rne(csh[kk4 + 3] * vsT[j][kk4 + 3]) << 16);
            *(uint2*)(cvT + ((size_t)b * NCV + j) * SS + k0 + kk4) = wv;
        }
        if (t < 16) {
            uint2 wv;
            wv.x = (uint)bf16rne(csh[t * 4 + 0]) | ((uint)bf16rne(csh[t * 4 + 1]) << 16);
            wv.y = (uint)bf16rne(csh[t * 4 + 2]) | ((uint)bf16rne(csh[t * 4 + 3]) << 16);
            *(uint2*)(cvT + ((size_t)b * NCV + 64) * SS + k0 + t * 4);
            *(uint2*)(cvT + ((size_t)b * NCV + 64) * SS + k0 + t * 4) = wv;
        }
    }
}

// K4: 16 q-rows/block, 256 thr (4 waves); wave w: k [512w, 512w+512).
// Phase A: stream score (one 16B load = D operand AND N A-frag), N MFMA, D fma.
// Then D reduce, N cross-wave reduce, out. Probs: row-by-row load->barrier->write
// (write clobbers that row's score after all threads have read it).
__global__ __launch_bounds__(256, 4) void k_final(
    const ushort* __restrict__ scrS, const ushort* __restrict__ cvT,
    float* __restrict__ probs, float* __restrict__ out)
{
    __shared__ float nred[16][64];     // 4 KB
    __shared__ float dPart[4][16];
    __shared__ float dInv[16];
    const int t = threadIdx.x;
    const int lane = t & 63;
    const int w = t >> 6;
    const int b = blockIdx.x >> 7;
    const int q0 = (blockIdx.x & 127) * 16;
    const int kbase = w * 512;
    const int qn = lane & 15;
    const int g = lane >> 4;

    ((float*)nred)[t] = 0.f; ((float*)nred)[t + 256] = 0.f;
    ((float*)nred)[t + 512] = 0.f; ((float*)nred)[t + 768] = 0.f;

    const ushort* cslice = cvT + (size_t)b * NCV * SS;
    const ushort* cbrow = cslice + (size_t)64 * SS;
    const ushort* srow = scrS + (size_t)(b * SS + q0 + qn) * 4096 + 2048;

    float dacc = 0.f;
    f32x4 nacc[4];
    #pragma unroll
    for (int ct = 0; ct < 4; ++ct) nacc[ct] = (f32x4){0.f, 0.f, 0.f, 0.f};

    #pragma unroll 2
    for (int ch = 0; ch < 16; ++ch) {
        const int ks0 = kbase + ch * 32;
        bf16x8 s8 = *(const bf16x8*)(srow + ks0 + g * 8);
        bf16x8 c8 = *(const bf16x8*)(cbrow + ks0 + g * 8);
        #pragma unroll
        for (int e = 0; e < 8; ++e)
            dacc = fmaf(bf2f((ushort)s8[e]), bf2f((ushort)c8[e]), dacc);
        #pragma unroll
        for (int ct = 0; ct < 4; ++ct) {
            bf16x8 bfv = *(const bf16x8*)(cslice + (size_t)(ct * 16 + qn) * SS + ks0 + g * 8);
            nacc[ct] = MFMA16(s8, bfv, nacc[ct]);
        }
    }
    // D reduce over g and waves
    {
        float d = dacc;
        d += __shfl_xor(d, 16, 64);
        d += __shfl_xor(d, 32, 64);
        if (lane < 16) dPart[w][lane] = d;
    }
    __syncthreads();
    if (t < 16) dInv[t] = 1.0f / (dPart[0][t] + dPart[1][t] + dPart[2][t] + dPart[3][t]);
    // N cross-wave reduce: nacc[ct][r] = N[q=g*4+r][d=ct*16+qn]
    #pragma unroll
    for (int ct = 0; ct < 4; ++ct)
        #pragma unroll
        for (int r = 0; r < 4; ++r)
            atomicAdd(&nred[g * 4 + r][ct * 16 + qn], nacc[ct][r]);
    __syncthreads();
    // out: 1024 values, 256 thr x 4
    {
        int q = t >> 4, c4 = (t & 15) * 4;
        float di = dInv[q];
        float4 o;
        o.x = nred[q][c4] * di;     o.y = nred[q][c4 + 1] * di;
        o.z = nred[q][c4 + 2] * di; o.w = nred[q][c4 + 3] * di;
        *(float4*)&out[(size_t)(b * SS + q0 + q) * DD + c4] = o;
    }
    // probs: row-by-row. thread t covers k = t*8..t*8+7 (256 thr x 8 = 2048).
    float cf[8];
    {
        bf16x8 c8 = *(const bf16x8*)(cbrow + t * 8);
        #pragma unroll
        for (int e = 0; e < 8; ++e) cf[e] = bf2f((ushort)c8[e]);
    }
    for (int r = 0; r < 16; ++r) {
        bf16x8 s8 = *(const bf16x8*)(scrS + (size_t)(b * SS + q0 + r) * 4096 + 2048 + t * 8);
        float di = dInv[r];
        __syncthreads();     // all reads of row r done before its probs write
        float4 o0, o1;
        o0.x = bf2f((ushort)s8[0]) * cf[0] * di;
        o0.y = bf2f((ushort)s8[1]) * cf[1] * di;
        o0.z = bf2f((ushort)s8[2]) * cf[2] * di;
        o0.w = bf2f((ushort)s8[3]) * cf[3] * di;
        o1.x = bf2f((ushort)s8[4]) * cf[4] * di;
        o1.y = bf2f((ushort)s8[5]) * cf[5] * di;
        o1.z = bf2f((ushort)s8[6]) * cf[6] * di;
        o1.w = bf2f((ushort)s8[7]) * cf[7] * di;
        float* prow = probs + (size_t)(b * SS + q0 + r) * SS + t * 8;
        *(float4*)prow = o0;
        *(float4*)(prow + 4) = o1;
    }
}

extern "C" void kernel_launch(void* const* d_in, const int* in_sizes, int n_in,
                              void* d_out, int out_size, void* d_ws, size_t ws_size,
                              hipStream_t stream)
{
    const float* x  = (const float*)d_in[0];
    const float* Wq = (const float*)d_in[1];
    const float* bq = (const float*)d_in[2];
    const float* Wk = (const float*)d_in[3];
    const float* bk = (const float*)d_in[4];
    const float* Wv = (const float*)d_in[5];
    const float* bv = (const float*)d_in[6];

    float* out   = (float*)d_out;                       // [8,2048,64]
    float* probs = out + (size_t)BB * SS * DD;          // [8,2048,2048]
    ushort* scrS = (ushort*)probs;                      // score bf16 interleaved in rows

    const size_t NQ = (size_t)BB * SS * DD;             // 1,048,576
    ushort* qh    = (ushort*)d_ws;
    ushort* ql    = qh + NQ;
    ushort* kh    = ql + NQ;
    ushort* kl    = kh + NQ;
    float*  vw    = (float*)(kl + NQ);
    ushort* cvT   = (ushort*)(vw + NQ);
    ushort* Whi   = cvT + (size_t)BB * NCV * SS;
    ushort* Wlo   = Whi + (size_t)192 * HH;
    float*  bcat  = (float*)(Wlo + (size_t)192 * HH);

    k_prep    <<<192, 256, 0, stream>>>(Wq, Wk, Wv, bq, bk, bv, Whi, Wlo, bcat);
    k_projmm  <<<512, 256, 0, stream>>>(x, Whi, Wlo, bcat, qh, ql, kh, kl, vw);
    k_score   <<<2048, 256, 0, stream>>>(qh, ql, kh, kl, scrS);
    k_csum_cvc<<<256, 256, 0, stream>>>(scrS, vw, cvT);
    k_final   <<<1024, 256, 0, stream>>>(scrS, cvT, probs, out);
}

// Round 7
// 221.634 us; speedup vs baseline: 1.2366x; 1.0072x over previous
//
#include <hip/hip_runtime.h>
#include <math.h>

#define BB 8
#define SS 2048
#define HH 1024
#define DD 64
#define NCV 65

typedef __attribute__((ext_vector_type(8))) short bf16x8;
typedef __attribute__((ext_vector_type(4))) float f32x4;
typedef __attribute__((ext_vector_type(16))) float f32x16;

#define MFMA16(a, b, c) __builtin_amdgcn_mfma_f32_16x16x32_bf16(a, b, c, 0, 0, 0)
#define MFMA32(a, b, c) __builtin_amdgcn_mfma_f32_32x32x16_bf16(a, b, c, 0, 0, 0)

__device__ __forceinline__ ushort bf16rne(float f) {
    uint u = __float_as_uint(f);
    uint r = (u + 0x7FFFu + ((u >> 16) & 1u)) >> 16;
    return (ushort)r;
}
__device__ __forceinline__ float bf2f(ushort h) {
    return __uint_as_float(((uint)h) << 16);
}

// score = (1 + acos(clip(cos)))^-65.5
__device__ __forceinline__ float score_fn(float cosv) {
    float ax = fminf(fabsf(cosv), 1.0f - 1e-7f);
    float p = fmaf(ax, -0.0012624911f, 0.0066700901f);
    p = fmaf(ax, p, -0.0170881256f);
    p = fmaf(ax, p, 0.0308918810f);
    p = fmaf(ax, p, -0.0501743046f);
    p = fmaf(ax, p, 0.0889789874f);
    p = fmaf(ax, p, -0.2145988016f);
    p = fmaf(ax, p, 1.5707963050f);
    float r = sqrtf(1.0f - ax) * p;                       // acos(|x|)
    float g = (cosv >= 0.0f) ? r : (3.14159265358979f - r);
    return exp2f(-65.5f * log2f(1.0f + g));
}

// K0: split W into bf16 hi/lo, layout Wcat[n][j], n = mat*64+d. Also bcat.
__global__ __launch_bounds__(256) void k_prep(
    const float* __restrict__ Wq, const float* __restrict__ Wk, const float* __restrict__ Wv,
    const float* __restrict__ bq, const float* __restrict__ bk, const float* __restrict__ bv,
    ushort* __restrict__ Whi, ushort* __restrict__ Wlo, float* __restrict__ bcat)
{
    const int n = blockIdx.x;          // 0..191
    const int m = n >> 6, d = n & 63;
    const float* W = (m == 0) ? Wq : (m == 1 ? Wk : Wv);
    #pragma unroll
    for (int i = 0; i < 4; ++i) {
        int j = i * 256 + threadIdx.x;
        float f = W[(size_t)j * DD + d];
        ushort h = bf16rne(f);
        Whi[(size_t)n * HH + j] = h;
        Wlo[(size_t)n * HH + j] = bf16rne(f - bf2f(h));
    }
    if (n == 0 && threadIdx.x < 192) {
        int t = threadIdx.x, mm = t >> 6, dd = t & 63;
        const float* b = (mm == 0) ? bq : (mm == 1 ? bk : bv);
        bcat[t] = b[dd];
    }
}

// K1: q,k,v = l2norm(x @ W + b) via split-bf16 MFMA.
__global__ __launch_bounds__(256) void k_projmm(
    const float* __restrict__ x, const ushort* __restrict__ Whi,
    const ushort* __restrict__ Wlo, const float* __restrict__ bcat,
    ushort* __restrict__ qh, ushort* __restrict__ ql,
    ushort* __restrict__ kh, ushort* __restrict__ kl,
    float* __restrict__ vw)
{
    __shared__ __align__(16) char smem[32 * 193 * 4];
    __shared__ float rns[96];
    __shared__ float bsh[192];
    ushort* xhi = (ushort*)smem;                 // [32][128] bf16, XOR-swizzled 16B units
    ushort* xlo = xhi + 32 * 128;
    float* ctile = (float*)smem;                 // [32][193] epilogue (aliases xhi/xlo)

    const int t = threadIdx.x;
    const int lane = t & 63;
    const int wid = t >> 6;
    const int row0 = blockIdx.x * 32;
    if (t < 192) bsh[t] = bcat[t];

    f32x4 acc[2][3];
    #pragma unroll
    for (int ar = 0; ar < 2; ++ar)
        #pragma unroll
        for (int bc = 0; bc < 3; ++bc)
            acc[ar][bc] = (f32x4){0.f, 0.f, 0.f, 0.f};

    for (int ch = 0; ch < 8; ++ch) {
        const int j0 = ch * 128;
        __syncthreads();
        #pragma unroll
        for (int i = 0; i < 2; ++i) {
            int u = i * 256 + t;
            int row = u >> 4, uc = u & 15;
            const float* xp = &x[(size_t)(row0 + row) * HH + j0 + uc * 8];
            float4 a = *(const float4*)xp;
            float4 b = *(const float4*)(xp + 4);
            float fs[8] = {a.x, a.y, a.z, a.w, b.x, b.y, b.z, b.w};
            bf16x8 hv, lv;
            #pragma unroll
            for (int e = 0; e < 8; ++e) {
                ushort h = bf16rne(fs[e]);
                hv[e] = (short)h;
                lv[e] = (short)bf16rne(fs[e] - bf2f(h));
            }
            int su = uc ^ (row & 7);
            *(bf16x8*)(xhi + row * 128 + su * 8) = hv;
            *(bf16x8*)(xlo + row * 128 + su * 8) = lv;
        }
        __syncthreads();
        #pragma unroll
        for (int ks = 0; ks < 4; ++ks) {
            bf16x8 ah[2], al[2], bh[3], bl[3];
            #pragma unroll
            for (int ar = 0; ar < 2; ++ar) {
                int row = ar * 16 + (lane & 15);
                int su = (ks * 4 + (lane >> 4)) ^ (row & 7);
                ah[ar] = *(const bf16x8*)(xhi + row * 128 + su * 8);
                al[ar] = *(const bf16x8*)(xlo + row * 128 + su * 8);
            }
            const int koff = j0 + ks * 32 + (lane >> 4) * 8;
            #pragma unroll
            for (int bc = 0; bc < 3; ++bc) {
                int n = wid * 48 + bc * 16 + (lane & 15);
                bh[bc] = *(const bf16x8*)(Whi + (size_t)n * HH + koff);
                bl[bc] = *(const bf16x8*)(Wlo + (size_t)n * HH + koff);
            }
            #pragma unroll
            for (int ar = 0; ar < 2; ++ar)
                #pragma unroll
                for (int bc = 0; bc < 3; ++bc) {
                    acc[ar][bc] = MFMA16(ah[ar], bh[bc], acc[ar][bc]);
                    acc[ar][bc] = MFMA16(ah[ar], bl[bc], acc[ar][bc]);
                    acc[ar][bc] = MFMA16(al[ar], bh[bc], acc[ar][bc]);
                }
        }
    }
    __syncthreads();
    #pragma unroll
    for (int ar = 0; ar < 2; ++ar)
        #pragma unroll
        for (int bc = 0; bc < 3; ++bc) {
            int n = wid * 48 + bc * 16 + (lane & 15);
            #pragma unroll
            for (int r = 0; r < 4; ++r) {
                int row = ar * 16 + (lane >> 4) * 4 + r;
                ctile[row * 193 + n] = acc[ar][bc][r];
            }
        }
    __syncthreads();
    if (t < 96) {
        int mat = t >> 5, row = t & 31;
        float ss = 0.f;
        #pragma unroll 8
        for (int d = 0; d < 64; ++d) {
            float v = ctile[row * 193 + mat * 64 + d] + bsh[mat * 64 + d];
            ss = fmaf(v, v, ss);
        }
        rns[t] = 1.0f / fmaxf(sqrtf(ss), 1e-12f);
    }
    __syncthreads();
    #pragma unroll
    for (int i = 0; i < 24; ++i) {
        int idx = i * 256 + t;
        int row = idx / 192;
        int n = idx - row * 192;
        float v = (ctile[row * 193 + n] + bsh[n]) * rns[(n >> 6) * 32 + row];
        size_t off = (size_t)(row0 + row) * DD + (n & 63);
        if (n < 64) {
            ushort h = bf16rne(v);
            qh[off] = h; ql[off] = bf16rne(v - bf2f(h));
        } else if (n < 128) {
            ushort h = bf16rne(v);
            kh[off] = h; kl[off] = bf16rne(v - bf2f(h));
        } else {
            vw[off] = v;
        }
    }
}

// K2: score(q,k) once -> bf16, stored in upper half of each probs row.
// 32x32x16 MFMA, swapped (A=K rows, B=Q cols). C: col=q(lane&31),
// row=k=(r&3)+8*(r>>2)+4*(lane>>5). Tile double-buffered in registers.
// Grid = 8b * 64qt(32) * 4ks = 2048 blocks, 256 thr. Wave w: k [ks*512+w*128, +128).
#define K_LOAD(H0,H1,H2,H3,L0,L1,L2,L3, KT) { \
    const ushort* kp = kh + (size_t)(b * SS + kbase + (KT) * 32 + qrow) * DD + kg; \
    const ushort* lp = kl + (size_t)(b * SS + kbase + (KT) * 32 + qrow) * DD + kg; \
    H0 = *(const bf16x8*)(kp);      L0 = *(const bf16x8*)(lp); \
    H1 = *(const bf16x8*)(kp + 16); L1 = *(const bf16x8*)(lp + 16); \
    H2 = *(const bf16x8*)(kp + 32); L2 = *(const bf16x8*)(lp + 32); \
    H3 = *(const bf16x8*)(kp + 48); L3 = *(const bf16x8*)(lp + 48); }

#define K_COMPUTE(H0,H1,H2,H3,L0,L1,L2,L3, KT) { \
    f32x16 acc = Z16; \
    acc = MFMA32(H0, qbh0, acc); acc = MFMA32(H0, qbl0, acc); acc = MFMA32(L0, qbh0, acc); \
    acc = MFMA32(H1, qbh1, acc); acc = MFMA32(H1, qbl1, acc); acc = MFMA32(L1, qbh1, acc); \
    acc = MFMA32(H2, qbh2, acc); acc = MFMA32(H2, qbl2, acc); acc = MFMA32(L2, qbh2, acc); \
    acc = MFMA32(H3, qbh3, acc); acc = MFMA32(H3, qbl3, acc); acc = MFMA32(L3, qbh3, acc); \
    const int kloc = kbase + (KT) * 32 + hi4; \
    uint2 wv; \
    wv.x = (uint)bf16rne(score_fn(acc[0]))  | ((uint)bf16rne(score_fn(acc[1]))  << 16); \
    wv.y = (uint)bf16rne(score_fn(acc[2]))  | ((uint)bf16rne(score_fn(acc[3]))  << 16); \
    *(uint2*)(srow + kloc) = wv; \
    wv.x = (uint)bf16rne(score_fn(acc[4]))  | ((uint)bf16rne(score_fn(acc[5]))  << 16); \
    wv.y = (uint)bf16rne(score_fn(acc[6]))  | ((uint)bf16rne(score_fn(acc[7]))  << 16); \
    *(uint2*)(srow + kloc + 8) = wv; \
    wv.x = (uint)bf16rne(score_fn(acc[8]))  | ((uint)bf16rne(score_fn(acc[9]))  << 16); \
    wv.y = (uint)bf16rne(score_fn(acc[10])) | ((uint)bf16rne(score_fn(acc[11])) << 16); \
    *(uint2*)(srow + kloc + 16) = wv; \
    wv.x = (uint)bf16rne(score_fn(acc[12])) | ((uint)bf16rne(score_fn(acc[13])) << 16); \
    wv.y = (uint)bf16rne(score_fn(acc[14])) | ((uint)bf16rne(score_fn(acc[15])) << 16); \
    *(uint2*)(srow + kloc + 24) = wv; }

__global__ __launch_bounds__(256, 4) void k_score(
    const ushort* __restrict__ qh, const ushort* __restrict__ ql,
    const ushort* __restrict__ kh, const ushort* __restrict__ kl,
    ushort* __restrict__ scrS)
{
    const int t = threadIdx.x;
    const int lane = t & 63;
    const int w = t >> 6;
    const int bid = blockIdx.x;
    const int b  = bid >> 8;
    const int q0 = ((bid >> 2) & 63) * 32;
    const int kbase = (bid & 3) * 512 + w * 128;
    const int qrow = lane & 31;
    const int kg = (lane >> 5) * 8;
    const int hi4 = (lane >> 5) * 4;
    const f32x16 Z16 = {0.f,0.f,0.f,0.f,0.f,0.f,0.f,0.f,0.f,0.f,0.f,0.f,0.f,0.f,0.f,0.f};

    const size_t qoff = (size_t)(b * SS + q0 + qrow) * DD + kg;
    bf16x8 qbh0 = *(const bf16x8*)(qh + qoff);
    bf16x8 qbh1 = *(const bf16x8*)(qh + qoff + 16);
    bf16x8 qbh2 = *(const bf16x8*)(qh + qoff + 32);
    bf16x8 qbh3 = *(const bf16x8*)(qh + qoff + 48);
    bf16x8 qbl0 = *(const bf16x8*)(ql + qoff);
    bf16x8 qbl1 = *(const bf16x8*)(ql + qoff + 16);
    bf16x8 qbl2 = *(const bf16x8*)(ql + qoff + 32);
    bf16x8 qbl3 = *(const bf16x8*)(ql + qoff + 48);
    ushort* srow = scrS + (size_t)(b * SS + q0 + qrow) * 4096 + 2048;

    bf16x8 xh0, xh1, xh2, xh3, xl0, xl1, xl2, xl3;
    bf16x8 yh0, yh1, yh2, yh3, yl0, yl1, yl2, yl3;
    K_LOAD(xh0,xh1,xh2,xh3,xl0,xl1,xl2,xl3, 0)
    K_LOAD(yh0,yh1,yh2,yh3,yl0,yl1,yl2,yl3, 1)
    K_COMPUTE(xh0,xh1,xh2,xh3,xl0,xl1,xl2,xl3, 0)
    K_LOAD(xh0,xh1,xh2,xh3,xl0,xl1,xl2,xl3, 2)
    K_COMPUTE(yh0,yh1,yh2,yh3,yl0,yl1,yl2,yl3, 1)
    K_LOAD(yh0,yh1,yh2,yh3,yl0,yl1,yl2,yl3, 3)
    K_COMPUTE(xh0,xh1,xh2,xh3,xl0,xl1,xl2,xl3, 2)
    K_COMPUTE(yh0,yh1,yh2,yh3,yl0,yl1,yl2,yl3, 3)
}

// K3: colsum over q (streaming) -> c = colsum^-0.5 (in-block) -> cvT build.
__global__ __launch_bounds__(256) void k_csum_cvc(
    const ushort* __restrict__ scrS, const float* __restrict__ vw,
    ushort* __restrict__ cvT)
{
    __shared__ float cls[32][64];
    __shared__ float csh[64];
    __shared__ float vsT[64][65];
    const int t = threadIdx.x;
    const int b = blockIdx.x >> 5;
    const int k0 = (blockIdx.x & 31) * 64;

    {
        const int tq = t >> 3, tk = t & 7;
        float colacc[8];
        #pragma unroll
        for (int e = 0; e < 8; ++e) colacc[e] = 0.f;
        #pragma unroll 4
        for (int it = 0; it < 64; ++it) {
            int q = it * 32 + tq;
            bf16x8 s8 = *(const bf16x8*)(scrS + (size_t)(b * SS + q) * 4096 + 2048 + k0 + tk * 8);
            #pragma unroll
            for (int e = 0; e < 8; ++e) colacc[e] += bf2f((ushort)s8[e]);
        }
        #pragma unroll
        for (int e = 0; e < 8; ++e) cls[tq][tk * 8 + e] = colacc[e];
    }
    __syncthreads();
    if (t < 64) {
        float s = 0.f;
        #pragma unroll
        for (int tq = 0; tq < 32; ++tq) s += cls[tq][t];
        csh[t] = 1.0f / sqrtf(s);
    }
    {
        const int j = t & 63, rr = t >> 6;
        #pragma unroll
        for (int it = 0; it < 16; ++it) {
            int kk = it * 4 + rr;
            vsT[j][kk] = vw[(size_t)(b * SS + k0 + kk) * DD + j];
        }
    }
    __syncthreads();
    {
        const int kk4 = (t & 15) * 4;
        #pragma unroll
        for (int jt = 0; jt < 4; ++jt) {
            int j = jt * 16 + (t >> 4);
            uint2 wv;
            wv.x = (uint)bf16rne(csh[kk4 + 0] * vsT[j][kk4 + 0])
                 | ((uint)bf16rne(csh[kk4 + 1] * vsT[j][kk4 + 1]) << 16);
            wv.y = (uint)bf16rne(csh[kk4 + 2] * vsT[j][kk4 + 2])
                 | ((uint)bf16rne(csh[kk4 + 3] * vsT[j][kk4 + 3]) << 16);
            *(uint2*)(cvT + ((size_t)b * NCV + j) * SS + k0 + kk4) = wv;
        }
        if (t < 16) {
            uint2 wv;
            wv.x = (uint)bf16rne(csh[t * 4 + 0]) | ((uint)bf16rne(csh[t * 4 + 1]) << 16);
            wv.y = (uint)bf16rne(csh[t * 4 + 2]) | ((uint)bf16rne(csh[t * 4 + 3]) << 16);
            *(uint2*)(cvT + ((size_t)b * NCV + 64) * SS + k0 + t * 4) = wv;
        }
    }
}

// K4: 32 q-rows/block, 256 thr (4 waves); wave w: k [512w, 512w+512).
// Phase A: 32x32x16 MFMA (A=score row-load, B=cvT cols), D fma alongside.
// Then D reduce, N cross-wave LDS reduce, out. Probs: 4-row batches.
__global__ __launch_bounds__(256, 4) void k_final(
    const ushort* __restrict__ scrS, const ushort* __restrict__ cvT,
    float* __restrict__ probs, float* __restrict__ out)
{
    __shared__ float nred[32][64];     // 8 KB
    __shared__ float dPart[4][32];
    __shared__ float dInv[32];
    const int t = threadIdx.x;
    const int lane = t & 63;
    const int w = t >> 6;
    const int b = blockIdx.x >> 6;
    const int q0 = (blockIdx.x & 63) * 32;
    const int kbase = w * 512;
    const int qrow = lane & 31;
    const int kg = (lane >> 5) * 8;
    const f32x16 Z16 = {0.f,0.f,0.f,0.f,0.f,0.f,0.f,0.f,0.f,0.f,0.f,0.f,0.f,0.f,0.f,0.f};

    #pragma unroll
    for (int i = 0; i < 8; ++i) ((float*)nred)[t + i * 256] = 0.f;
    __syncthreads();

    const ushort* cslice = cvT + (size_t)b * NCV * SS;
    const ushort* cbrow = cslice + (size_t)64 * SS;
    const ushort* srow = scrS + (size_t)(b * SS + q0 + qrow) * 4096 + 2048;

    float dacc = 0.f;
    f32x16 n0 = Z16, n1 = Z16;

    #pragma unroll 4
    for (int ch = 0; ch < 32; ++ch) {
        const int kc = kbase + ch * 16 + kg;
        bf16x8 s8 = *(const bf16x8*)(srow + kc);
        bf16x8 c8 = *(const bf16x8*)(cbrow + kc);
        bf16x8 b0 = *(const bf16x8*)(cslice + (size_t)qrow * SS + kc);
        bf16x8 b1 = *(const bf16x8*)(cslice + (size_t)(32 + qrow) * SS + kc);
        #pragma unroll
        for (int e = 0; e < 8; ++e)
            dacc = fmaf(bf2f((ushort)s8[e]), bf2f((ushort)c8[e]), dacc);
        n0 = MFMA32(s8, b0, n0);
        n1 = MFMA32(s8, b1, n1);
    }
    // D reduce: lanes l and l+32 share qrow
    {
        float d = dacc;
        d += __shfl_xor(d, 32, 64);
        if (lane < 32) dPart[w][lane] = d;
    }
    __syncthreads();
    if (t < 32) dInv[t] = 1.0f / (dPart[0][t] + dPart[1][t] + dPart[2][t] + dPart[3][t]);
    // N cross-wave reduce: n0[r] = N[q=(r&3)+8*(r>>2)+4*(lane>>5)][d=qrow]
    #pragma unroll
    for (int r = 0; r < 16; ++r) {
        int q = (r & 3) + 8 * (r >> 2) + 4 * (lane >> 5);
        atomicAdd(&nred[q][qrow], n0[r]);
        atomicAdd(&nred[q][32 + qrow], n1[r]);
    }
    __syncthreads();
    // out: 2048 values, 256 thr x 8
    {
        int q = t >> 3, d0 = (t & 7) * 8;
        float di = dInv[q];
        float4 o0, o1;
        o0.x = nred[q][d0 + 0] * di; o0.y = nred[q][d0 + 1] * di;
        o0.z = nred[q][d0 + 2] * di; o0.w = nred[q][d0 + 3] * di;
        o1.x = nred[q][d0 + 4] * di; o1.y = nred[q][d0 + 5] * di;
        o1.z = nred[q][d0 + 6] * di; o1.w = nred[q][d0 + 7] * di;
        float* op = &out[(size_t)(b * SS + q0 + q) * DD + d0];
        *(float4*)op = o0;
        *(float4*)(op + 4) = o1;
    }
    // probs: 4-row batches; thread t covers k = t*8..t*8+7.
    float cf[8];
    {
        bf16x8 c8 = *(const bf16x8*)(cbrow + t * 8);
        #pragma unroll
        for (int e = 0; e < 8; ++e) cf[e] = bf2f((ushort)c8[e]);
    }
#define P_STORE(S8, DI, RR) { \
    float4 o0, o1; \
    o0.x = bf2f((ushort)S8[0]) * cf[0] * DI; \
    o0.y = bf2f((ushort)S8[1]) * cf[1] * DI; \
    o0.z = bf2f((ushort)S8[2]) * cf[2] * DI; \
    o0.w = bf2f((ushort)S8[3]) * cf[3] * DI; \
    o1.x = bf2f((ushort)S8[4]) * cf[4] * DI; \
    o1.y = bf2f((ushort)S8[5]) * cf[5] * DI; \
    o1.z = bf2f((ushort)S8[6]) * cf[6] * DI; \
    o1.w = bf2f((ushort)S8[7]) * cf[7] * DI; \
    float* prow = probs + (size_t)(b * SS + q0 + (RR)) * SS + t * 8; \
    *(float4*)prow = o0; \
    *(float4*)(prow + 4) = o1; }

    #pragma unroll
    for (int r0 = 0; r0 < 32; r0 += 4) {
        bf16x8 sA = *(const bf16x8*)(scrS + (size_t)(b * SS + q0 + r0 + 0) * 4096 + 2048 + t * 8);
        bf16x8 sB = *(const bf16x8*)(scrS + (size_t)(b * SS + q0 + r0 + 1) * 4096 + 2048 + t * 8);
        bf16x8 sC = *(const bf16x8*)(scrS + (size_t)(b * SS + q0 + r0 + 2) * 4096 + 2048 + t * 8);
        bf16x8 sD = *(const bf16x8*)(scrS + (size_t)(b * SS + q0 + r0 + 3) * 4096 + 2048 + t * 8);
        float dA = dInv[r0 + 0], dB = dInv[r0 + 1], dC = dInv[r0 + 2], dD = dInv[r0 + 3];
        __syncthreads();   // all reads of rows r0..r0+3 done before their probs writes
        P_STORE(sA, dA, r0 + 0)
        P_STORE(sB, dB, r0 + 1)
        P_STORE(sC, dC, r0 + 2)
        P_STORE(sD, dD, r0 + 3)
    }
}

extern "C" void kernel_launch(void* const* d_in, const int* in_sizes, int n_in,
                              void* d_out, int out_size, void* d_ws, size_t ws_size,
                              hipStream_t stream)
{
    const float* x  = (const float*)d_in[0];
    const float* Wq = (const float*)d_in[1];
    const float* bq = (const float*)d_in[2];
    const float* Wk = (const float*)d_in[3];
    const float* bk = (const float*)d_in[4];
    const float* Wv = (const float*)d_in[5];
    const float* bv = (const float*)d_in[6];

    float* out   = (float*)d_out;                       // [8,2048,64]
    float* probs = out + (size_t)BB * SS * DD;          // [8,2048,2048]
    ushort* scrS = (ushort*)probs;                      // score bf16 in row upper halves

    const size_t NQ = (size_t)BB * SS * DD;             // 1,048,576
    ushort* qh    = (ushort*)d_ws;
    ushort* ql    = qh + NQ;
    ushort* kh    = ql + NQ;
    ushort* kl    = kh + NQ;
    float*  vw    = (float*)(kl + NQ);
    ushort* cvT   = (ushort*)(vw + NQ);
    ushort* Whi   = cvT + (size_t)BB * NCV * SS;
    ushort* Wlo   = Whi + (size_t)192 * HH;
    float*  bcat  = (float*)(Wlo + (size_t)192 * HH);

    k_prep    <<<192, 256, 0, stream>>>(Wq, Wk, Wv, bq, bk, bv, Whi, Wlo, bcat);
    k_projmm  <<<512, 256, 0, stream>>>(x, Whi, Wlo, bcat, qh, ql, kh, kl, vw);
    k_score   <<<2048, 256, 0, stream>>>(qh, ql, kh, kl, scrS);
    k_csum_cvc<<<256, 256, 0, stream>>>(scrS, vw, cvT);
    k_final   <<<512, 256, 0, stream>>>(scrS, cvT, probs, out);
}